// Round 6
// baseline (541.670 us; speedup 1.0000x reference)
//
#include <hip/hip_runtime.h>

#define NPTS   32768
#define NCODES 8192
#define DIM    256

#define DECAYF 0.99f
#define ONE_MINUS_DECAYF ((float)(1.0 - 0.99))
#define EPSF   1e-5f
#define KEPSF  ((float)(8192.0 * 1e-5))
#define MARGIN 0.03f

// workspace byte offsets
#define WS_PART  0                                     // fp64 [8192] loss partials
#define WS_A     (WS_PART + NPTS / 4 * 8)              // fp32 [NPTS]
#define WS_EN    (WS_A + NPTS * 4)                     // fp32 [NCODES]
#define WS_CNT   (WS_EN + NCODES * 4)                  // int  [NCODES]
#define WS_S     (WS_CNT + NCODES * 4)                 // fp32 [NCODES] smoothed
#define WS_IDX   (WS_S + NCODES * 4)                   // int  [NPTS]
#define WS_OFFS  (WS_IDX + NPTS * 4)                   // int  [NCODES]
#define WS_CUR   (WS_OFFS + NCODES * 4)                // int  [NCODES]
#define WS_PLIST (WS_CUR + NCODES * 4)                 // int  [NPTS]
#define WS_EMBT  (WS_PLIST + NPTS * 4)                 // fp32 embT[256][8192]   8 MB
#define WS_STOP2 (WS_EMBT + (size_t)DIM * NCODES * 4)  // 16B  [NPTS][64]       32 MB
#define WS_GMIN  (WS_STOP2 + (size_t)NPTS * 64 * 16)   // fp32 [NPTS][512]      64 MB
#define WS_AH    (WS_GMIN + (size_t)NPTS * 512 * 4)    // bf16 [NPTS][256]      16 MB
#define WS_BH    (WS_AH + (size_t)NPTS * DIM * 2)      // bf16 [NCODES][256]     4 MB

typedef __attribute__((ext_vector_type(8))) short short8;
typedef __attribute__((ext_vector_type(4))) float f32x4;

struct __align__(16) SE2 {
    unsigned long long pk;  // (ord(m1)<<32) | best_code
    float m2;               // second-best approx distance in strip
    float pad;
};

__device__ inline void gl_lds16(const void* g, void* l) {
    __builtin_amdgcn_global_load_lds(
        (const __attribute__((address_space(1))) void*)g,
        (__attribute__((address_space(3))) void*)l, 16, 0, 0);
}

__device__ inline unsigned short f2bf(float f) {  // RNE float->bf16
    unsigned u = __float_as_uint(f);
    return (unsigned short)((u + 0x7FFFu + ((u >> 16) & 1u)) >> 16);
}
__device__ inline unsigned f2ord(float f) {       // monotone float->uint
    unsigned u = __float_as_uint(f);
    return (u & 0x80000000u) ? ~u : (u | 0x80000000u);
}
__device__ inline float ord2f(unsigned o) {
    unsigned u = (o & 0x80000000u) ? (o & 0x7FFFFFFFu) : ~o;
    return __uint_as_float(u);
}

// ---------------------------------------------------------------------------
__global__ __launch_bounds__(256) void k_prep0(int* __restrict__ cnt) {
    int i = blockIdx.x * blockDim.x + threadIdx.x;
    if (i < NCODES) cnt[i] = 0;
}

// ---------------------------------------------------------------------------
__global__ __launch_bounds__(256) void k_rownorm(const float* __restrict__ x,
                                                 float* __restrict__ outn,
                                                 int nrows) {
    int w = (blockIdx.x * blockDim.x + threadIdx.x) >> 6;
    int lane = threadIdx.x & 63;
    if (w >= nrows) return;
    const float4 v = *(const float4*)(x + (size_t)w * DIM + 4 * lane);
    float q0 = v.x * v.x, q1 = v.y * v.y, q2 = v.z * v.z, q3 = v.w * v.w;
    double s = (double)q0 + (double)q1 + (double)q2 + (double)q3;
    #pragma unroll
    for (int off = 32; off > 0; off >>= 1) s += __shfl_down(s, off);
    if (lane == 0) outn[w] = (float)s;
}

// ---------------------------------------------------------------------------
// elementwise fp32 -> bf16-hi
__global__ __launch_bounds__(256) void k_split(const float* __restrict__ x,
                                               unsigned short* __restrict__ dst,
                                               int nelem) {
    int i = blockIdx.x * blockDim.x + threadIdx.x;
    int stride = gridDim.x * blockDim.x;
    for (int j = i; j < nelem; j += stride)
        dst[j] = f2bf(x[j]);
}

// ---------------------------------------------------------------------------
// transpose emb [8192][256] -> embT [256][8192] (fp32, bit-preserving)
__global__ __launch_bounds__(256) void k_transpose(const float* __restrict__ emb,
                                                   float* __restrict__ embT) {
    __shared__ float tile[32][33];
    int c0 = blockIdx.x * 32, d0 = blockIdx.y * 32;
    int tx = threadIdx.x & 31, ty = threadIdx.x >> 5;  // 8 rows
    #pragma unroll
    for (int r = 0; r < 4; ++r)
        tile[ty + r * 8][tx] = emb[(size_t)(c0 + ty + r * 8) * DIM + d0 + tx];
    __syncthreads();
    #pragma unroll
    for (int r = 0; r < 4; ++r)
        embT[(size_t)(d0 + ty + r * 8) * NCODES + c0 + tx] = tile[tx][ty + r * 8];
}

// ---------------------------------------------------------------------------
// Phase 1: bf16-hi MFMA GEMM (M=32768, N=8192, K=256). Epilogue writes
// (a) per-16-code-group min -> gmin[NPTS][512]
// (b) per-128-code-strip top-2 (value+idx, second value) -> stop2[NPTS][64]
__global__ __launch_bounds__(256) void k_gemm_argmin(
    const unsigned short* __restrict__ Ah,    // [NPTS][256] bf16 bits
    const unsigned short* __restrict__ Bh,    // [NCODES][256] bf16 bits
    const float* __restrict__ en,
    float* __restrict__ gmin,                 // [NPTS][512]
    SE2* __restrict__ stop2) {                // [NPTS][64]
    __shared__ __align__(16) unsigned short SBUF[16384];  // 32 KB: A | B

    const int t = threadIdx.x;
    const int w = t >> 6, l = t & 63;
    const int quad = l >> 4, l15 = l & 15;
    const int wr = w >> 1, wc = w & 1;
    const int mb = blockIdx.x >> 6, nb = blockIdx.x & 63;
    const int mBase = mb * 128, nBase = nb * 128;

    // staging swizzle: slot s covers (row=s>>3, x=s&7, kchunk = x ^ (row&7))
    const int xr = (t & 7) ^ ((t >> 3) & 7);
    const int rrow = t >> 3;
    const unsigned short* ag[4];
    const unsigned short* bg[4];
    #pragma unroll
    for (int i = 0; i < 4; ++i) {
        ag[i] = Ah + (size_t)(mBase + i * 32 + rrow) * DIM + xr * 8;
        bg[i] = Bh + (size_t)(nBase + i * 32 + rrow) * DIM + xr * 8;
    }

    f32x4 acc[4][4];
    #pragma unroll
    for (int i = 0; i < 4; ++i)
        #pragma unroll
        for (int j = 0; j < 4; ++j)
            acc[i][j] = (f32x4){0.f, 0.f, 0.f, 0.f};

    for (int kt = 0; kt < 4; ++kt) {
        __syncthreads();
        #pragma unroll
        for (int i = 0; i < 4; ++i) {
            gl_lds16(ag[i], &SBUF[(i * 256 + w * 64) * 8]);
            gl_lds16(bg[i], &SBUF[8192 + (i * 256 + w * 64) * 8]);
            ag[i] += 64; bg[i] += 64;
        }
        __syncthreads();
        #pragma unroll
        for (int kk = 0; kk < 2; ++kk) {
            const int kc = kk * 4 + quad;
            short8 a[4], b[4];
            #pragma unroll
            for (int ti = 0; ti < 4; ++ti) {
                int m = wr * 64 + ti * 16 + l15;
                a[ti] = *(const short8*)&SBUF[(m * 8 + (kc ^ (m & 7))) * 8];
                int n = wc * 64 + ti * 16 + l15;
                b[ti] = *(const short8*)&SBUF[8192 + (n * 8 + (kc ^ (n & 7))) * 8];
            }
            #pragma unroll
            for (int ti = 0; ti < 4; ++ti)
                #pragma unroll
                for (int tj = 0; tj < 4; ++tj)
                    acc[ti][tj] = __builtin_amdgcn_mfma_f32_16x16x32_bf16(
                        a[ti], b[tj], acc[ti][tj], 0, 0, 0);
        }
    }

    float enc[4];
    #pragma unroll
    for (int tj = 0; tj < 4; ++tj)
        enc[tj] = en[nBase + wc * 64 + tj * 16 + l15];

    __syncthreads();
    float* ov = (float*)SBUF;                       // [2][128][16] = 16 KB
    SE2* se = (SE2*)((char*)SBUF + 16384);          // [2][128]     =  4 KB

    #pragma unroll
    for (int ti = 0; ti < 4; ++ti) {
        #pragma unroll
        for (int r = 0; r < 4; ++r) {
            // 4 approx distances for codes nBase + wc*64 + tj*16 + l15
            float v[4];
            unsigned long long pk4[4];
            #pragma unroll
            for (int tj = 0; tj < 4; ++tj) {
                v[tj] = enc[tj] - 2.0f * acc[ti][tj][r];
                unsigned code = (unsigned)(nBase + wc * 64 + tj * 16 + l15);
                pk4[tj] = ((unsigned long long)f2ord(v[tj]) << 32) | code;
            }
            int p = wr * 64 + ti * 16 + quad * 4 + r;
            // (a) group-min staging
            float dmin = fminf(fminf(v[0], v[1]), fminf(v[2], v[3]));
            ov[(wc * 128 + p) * 16 + l15] = dmin;
            // (b) per-lane top2-of-4
            float s01 = fminf(v[0], v[1]), l01 = fmaxf(v[0], v[1]);
            float s23 = fminf(v[2], v[3]), l23 = fmaxf(v[2], v[3]);
            float v1 = fminf(s01, s23);
            float m2 = fminf(fmaxf(s01, s23), fminf(l01, l23));
            unsigned long long pk = pk4[0];
            #pragma unroll
            for (int tj = 1; tj < 4; ++tj) pk = pk4[tj] < pk ? pk4[tj] : pk;
            // merge across the 16 lanes holding this point's 64 cols
            #pragma unroll
            for (int m = 1; m < 16; m <<= 1) {
                unsigned long long opk = __shfl_xor(pk, m);
                float ov1 = __shfl_xor(v1, m);
                float om2 = __shfl_xor(m2, m);
                m2 = fminf(fminf(m2, om2), fmaxf(v1, ov1));
                v1 = fminf(v1, ov1);
                pk = opk < pk ? opk : pk;
            }
            if (l15 == 0) {
                se[wc * 128 + p].pk = pk;
                se[wc * 128 + p].m2 = m2;
                se[wc * 128 + p].pad = v1;
            }
        }
    }
    __syncthreads();
    // (a) finalize group minima
    #pragma unroll
    for (int it = 0; it < 4; ++it) {
        int id = it * 256 + t;                 // (wcc*128 + p)*4 + sg
        int sg = id & 3;
        const float4 vv = *(const float4*)&ov[(id >> 2) * 16 + sg * 4];
        float m = fminf(fminf(vv.x, vv.y), fminf(vv.z, vv.w));
        int pp = (id >> 2) & 127;
        int wcc = id >> 9;
        gmin[(size_t)(mBase + pp) * 512 + nb * 8 + wcc * 4 + sg] = m;
    }
    // (b) finalize strip top-2
    if (t < 128) {
        SE2 a0 = se[t], b0 = se[128 + t];
        float v1a = a0.pad, v1b = b0.pad;
        SE2 o;
        o.pk = a0.pk < b0.pk ? a0.pk : b0.pk;
        o.m2 = fminf(fminf(a0.m2, b0.m2), fmaxf(v1a, v1b));
        o.pad = 0.f;
        stop2[(size_t)(mBase + t) * 64 + nb] = o;
    }
}

// ---------------------------------------------------------------------------
// Phase 2: one wave per point. Certify via strip top-2 (zero extra traffic
// for ~90% of points); else exact-rescore flagged 16-code groups with
// round-1 fp32 BLAS semantics (unchanged from validated R3-R5 path).
__global__ __launch_bounds__(256) void k_phase2(
    const float* __restrict__ z, const float* __restrict__ embT,
    const float* __restrict__ A, const float* __restrict__ en,
    const SE2* __restrict__ stop2, const float* __restrict__ gmin,
    int* __restrict__ widx, float* __restrict__ out1,
    int* __restrict__ cnt) {
    int wpt = (blockIdx.x << 2) + (threadIdx.x >> 6);  // point id
    int l = threadIdx.x & 63;

    SE2 e = stop2[(size_t)wpt * 64 + l];
    unsigned long long g = e.pk;
    #pragma unroll
    for (int off = 1; off < 64; off <<= 1) {
        unsigned long long o = __shfl_xor(g, off);
        g = o < g ? o : g;
    }
    float g1v = ord2f((unsigned)(g >> 32));
    // second-best overall: winner strip contributes m2, others their m1
    float sec = (e.pk == g) ? e.m2 : ord2f((unsigned)(e.pk >> 32));
    #pragma unroll
    for (int off = 1; off < 64; off <<= 1) sec = fminf(sec, __shfl_xor(sec, off));

    if (sec - g1v > MARGIN) {   // certified unique fp32 argmin
        if (l == 0) {
            int idx = (int)(unsigned)g;
            widx[wpt] = idx;
            out1[wpt] = (float)idx;
            atomicAdd(cnt + idx, 1);
        }
        return;
    }

    // rescue: exact rescore of flagged 16-code groups
    const float* gp = gmin + (size_t)wpt * 512;
    float loc[8];
    #pragma unroll
    for (int i = 0; i < 8; ++i) loc[i] = gp[i * 64 + l];
    const float thresh = g1v + MARGIN;

    const float* zr = z + (size_t)wpt * DIM;
    const float Azn = A[wpt];
    unsigned long long best = ~0ull;
    #pragma unroll 1
    for (int i = 0; i < 8; ++i) {
        unsigned long long mask = __ballot(loc[i] <= thresh);
        while (mask) {
            int s = __ffsll((long long)mask) - 1;
            mask &= mask - 1;
            int gid = i * 64 + s;
            int cbase = (gid >> 3) * 128 + ((gid >> 2) & 1) * 64 + (gid & 3) * 4;
            int k = l & 15;
            int c = cbase + (k >> 2) * 16 + (k & 3);
            const float* ec = embT + c;
            float acc = 0.f;
            for (int d = 0; d < DIM; ++d)
                acc = fmaf(zr[d], ec[(size_t)d * NCODES], acc);
            float dist = (Azn - 2.0f * acc) + en[c];
            if (l < 16) {
                unsigned long long pk =
                    ((unsigned long long)f2ord(dist) << 32) | (unsigned)c;
                best = pk < best ? pk : best;
            }
        }
    }
    #pragma unroll
    for (int off = 1; off < 64; off <<= 1) {
        unsigned long long o = __shfl_xor(best, off);
        best = o < best ? o : best;
    }
    if (l == 0) {
        int idx = (int)(unsigned)best;
        widx[wpt] = idx;
        out1[wpt] = (float)idx;
        atomicAdd(cnt + idx, 1);
    }
}

// ---------------------------------------------------------------------------
// single block: exclusive prefix of cnt -> offs (+cursor copy);
// out4 = ecs*0.99 + cnt*0.01; n = sum(out4); smoothed -> s_out.
__global__ __launch_bounds__(256) void k_scan(const int* __restrict__ cnt,
                                              const float* __restrict__ ecs,
                                              int* __restrict__ offs,
                                              int* __restrict__ cursor,
                                              float* __restrict__ out4,
                                              float* __restrict__ s_out) {
    __shared__ int ps[256];
    __shared__ double rd[256];
    __shared__ float nsh;
    int t = threadIdx.x;
    int base = t * 32;
    int loc[32];
    int s = 0;
    double nl = 0.0;
    #pragma unroll
    for (int i = 0; i < 32; ++i) {
        int c = cnt[base + i];
        loc[i] = c;
        s += c;
        float f = ecs[base + i] * DECAYF + (float)c * ONE_MINUS_DECAYF;
        out4[base + i] = f;
        nl += (double)f;
    }
    ps[t] = s;
    rd[t] = nl;
    __syncthreads();
    for (int off = 1; off < 256; off <<= 1) {
        int v = (t >= off) ? ps[t - off] : 0;
        __syncthreads();
        ps[t] += v;
        __syncthreads();
    }
    for (int off = 128; off > 0; off >>= 1) {
        if (t < off) rd[t] += rd[t + off];
        __syncthreads();
    }
    if (t == 0) nsh = (float)rd[0];
    __syncthreads();
    int run = (t == 0) ? 0 : ps[t - 1];
    #pragma unroll
    for (int i = 0; i < 32; ++i) {
        offs[base + i] = run;
        cursor[base + i] = run;
        run += loc[i];
    }
    float n = nsh;
    for (int k = t; k < NCODES; k += 256)
        s_out[k] = (out4[k] + EPSF) / (n + KEPSF) * n;
}

// ---------------------------------------------------------------------------
__global__ __launch_bounds__(256) void k_place(const int* __restrict__ widx,
                                               int* __restrict__ cursor,
                                               int* __restrict__ plist) {
    int p = blockIdx.x * 256 + threadIdx.x;
    int idx = widx[p];
    int slot = atomicAdd(&cursor[idx], 1);
    plist[slot] = p;
}

// ---------------------------------------------------------------------------
// z_q_st + commitment-loss partials (no atomics; one double per block)
__global__ __launch_bounds__(256) void k_zq(const float* __restrict__ z,
                                            const float* __restrict__ emb,
                                            const int* __restrict__ widx,
                                            float* __restrict__ out0,
                                            double* __restrict__ part) {
    __shared__ double sred[4];
    int w = (blockIdx.x * blockDim.x + threadIdx.x) >> 6;  // point id
    int wv = threadIdx.x >> 6;
    int lane = threadIdx.x & 63;
    int idx = widx[w];
    const float4 zv = *(const float4*)(z + (size_t)w * DIM + 4 * lane);
    const float4 ev = *(const float4*)(emb + (size_t)idx * DIM + 4 * lane);

    float4 o;
    o.x = ev.x + (zv.x - ev.x);
    o.y = ev.y + (zv.y - ev.y);
    o.z = ev.z + (zv.z - ev.z);
    o.w = ev.w + (zv.w - ev.w);
    *(float4*)(out0 + (size_t)w * DIM + 4 * lane) = o;

    float t0 = ev.x - zv.x, t1 = ev.y - zv.y, t2 = ev.z - zv.z, t3 = ev.w - zv.w;
    float s0 = t0 * t0, s1 = t1 * t1, s2 = t2 * t2, s3 = t3 * t3;
    double ls = (double)s0 + (double)s1 + (double)s2 + (double)s3;
    #pragma unroll
    for (int off = 32; off > 0; off >>= 1) ls += __shfl_down(ls, off);
    if (lane == 0) sred[wv] = ls;
    __syncthreads();
    if (threadIdx.x == 0)
        part[blockIdx.x] = (sred[0] + sred[1]) + (sred[2] + sred[3]);
}

// ---------------------------------------------------------------------------
// single block: sum 8192 loss partials -> out2
__global__ __launch_bounds__(256) void k_loss(const double* __restrict__ part,
                                              float* __restrict__ out2) {
    __shared__ double red[256];
    int t = threadIdx.x;
    double s = 0.0;
    for (int i = t; i < NPTS / 4; i += 256) s += part[i];
    red[t] = s;
    __syncthreads();
    for (int off = 128; off > 0; off >>= 1) {
        if (t < off) red[t] += red[t + off];
        __syncthreads();
    }
    if (t == 0)
        out2[0] = 0.25f * (float)(red[0] / (double)((size_t)NPTS * DIM));
}

// ---------------------------------------------------------------------------
// one wave per code: out5 = 0.99*eem + 0.01*sum(z[points of code])
__global__ __launch_bounds__(256) void k_dw(const float* __restrict__ z,
                                            const float* __restrict__ eem,
                                            const int* __restrict__ offs,
                                            const int* __restrict__ cnt,
                                            const int* __restrict__ plist,
                                            float* __restrict__ out5) {
    int c = blockIdx.x * 4 + (threadIdx.x >> 6);
    int lane = threadIdx.x & 63;
    int beg = offs[c], num = cnt[c];
    float4 acc = make_float4(0.f, 0.f, 0.f, 0.f);
    for (int j = 0; j < num; ++j) {
        int p = plist[beg + j];
        const float4 v = *(const float4*)(z + (size_t)p * DIM + 4 * lane);
        acc.x += v.x; acc.y += v.y; acc.z += v.z; acc.w += v.w;
    }
    const float4 e = *(const float4*)(eem + (size_t)c * DIM + 4 * lane);
    float4 o;
    o.x = e.x * DECAYF + acc.x * ONE_MINUS_DECAYF;
    o.y = e.y * DECAYF + acc.y * ONE_MINUS_DECAYF;
    o.z = e.z * DECAYF + acc.z * ONE_MINUS_DECAYF;
    o.w = e.w * DECAYF + acc.w * ONE_MINUS_DECAYF;
    *(float4*)(out5 + (size_t)c * DIM + 4 * lane) = o;
}

// ---------------------------------------------------------------------------
__global__ __launch_bounds__(256) void k_final(const float* __restrict__ out5,
                                               const float* __restrict__ s,
                                               float* __restrict__ out3) {
    int i = blockIdx.x * blockDim.x + threadIdx.x;
    int stride = gridDim.x * blockDim.x;
    for (int j = i; j < NCODES * DIM; j += stride)
        out3[j] = out5[j] / s[j >> 8];
}

// ---------------------------------------------------------------------------
extern "C" void kernel_launch(void* const* d_in, const int* in_sizes, int n_in,
                              void* d_out, int out_size, void* d_ws, size_t ws_size,
                              hipStream_t stream) {
    const float* z   = (const float*)d_in[0];
    const float* emb = (const float*)d_in[1];
    const float* ecs = (const float*)d_in[2];
    const float* eem = (const float*)d_in[3];

    float* out = (float*)d_out;
    float* out0 = out;                   // z_q_st         [8388608]
    float* out1 = out + 8388608;         // indices        [32768]
    float* out2 = out + 8421376;         // vq_loss        [1]
    float* out3 = out + 8421377;         // new_embedding  [2097152]
    float* out4 = out + 10518529;        // new_ema_cs     [8192]
    float* out5 = out + 10526721;        // new_ema_emb    [2097152]

    char* ws = (char*)d_ws;
    double* wPart = (double*)(ws + WS_PART);
    float*  wA    = (float*)(ws + WS_A);
    float*  wEn   = (float*)(ws + WS_EN);
    int*    wCnt  = (int*)(ws + WS_CNT);
    float*  wS    = (float*)(ws + WS_S);
    int*    wIdx  = (int*)(ws + WS_IDX);
    int*    wOffs = (int*)(ws + WS_OFFS);
    int*    wCur  = (int*)(ws + WS_CUR);
    int*    wPl   = (int*)(ws + WS_PLIST);
    float*  wEmbT = (float*)(ws + WS_EMBT);
    SE2*    wS2   = (SE2*)(ws + WS_STOP2);
    float*  wGmin = (float*)(ws + WS_GMIN);
    unsigned short* wAh = (unsigned short*)(ws + WS_AH);
    unsigned short* wBh = (unsigned short*)(ws + WS_BH);

    hipLaunchKernelGGL(k_prep0, dim3(32), dim3(256), 0, stream, wCnt);
    hipLaunchKernelGGL(k_rownorm, dim3(NPTS / 4), dim3(256), 0, stream, z, wA, NPTS);
    hipLaunchKernelGGL(k_rownorm, dim3(NCODES / 4), dim3(256), 0, stream, emb, wEn, NCODES);
    hipLaunchKernelGGL(k_split, dim3(4096), dim3(256), 0, stream, z, wAh, NPTS * DIM);
    hipLaunchKernelGGL(k_split, dim3(1024), dim3(256), 0, stream, emb, wBh, NCODES * DIM);
    hipLaunchKernelGGL(k_transpose, dim3(256, 8), dim3(256), 0, stream, emb, wEmbT);
    hipLaunchKernelGGL(k_gemm_argmin, dim3((NPTS / 128) * (NCODES / 128)), dim3(256), 0, stream,
                       wAh, wBh, wEn, wGmin, wS2);
    hipLaunchKernelGGL(k_phase2, dim3(NPTS / 4), dim3(256), 0, stream,
                       z, wEmbT, wA, wEn, wS2, wGmin, wIdx, out1, wCnt);
    hipLaunchKernelGGL(k_scan, dim3(1), dim3(256), 0, stream,
                       wCnt, ecs, wOffs, wCur, out4, wS);
    hipLaunchKernelGGL(k_place, dim3(NPTS / 256), dim3(256), 0, stream, wIdx, wCur, wPl);
    hipLaunchKernelGGL(k_zq, dim3(NPTS / 4), dim3(256), 0, stream, z, emb, wIdx, out0, wPart);
    hipLaunchKernelGGL(k_loss, dim3(1), dim3(256), 0, stream, wPart, out2);
    hipLaunchKernelGGL(k_dw, dim3(NCODES / 4), dim3(256), 0, stream,
                       z, eem, wOffs, wCnt, wPl, out5);
    hipLaunchKernelGGL(k_final, dim3(2048), dim3(256), 0, stream, out5, wS, out3);
}